// Round 6
// baseline (638.832 us; speedup 1.0000x reference)
//
#include <hip/hip_runtime.h>

#define BB 4
#define SS 2048
#define DDIM 512
#define HH 8
#define MTOK (BB*SS)   // 8192
#define BHN (BB*HH)    // 32

typedef _Float16 f16;
typedef __attribute__((ext_vector_type(8))) _Float16 half8;
typedef __attribute__((ext_vector_type(4))) _Float16 half4;
typedef __attribute__((ext_vector_type(4))) float float4v;
typedef __attribute__((ext_vector_type(4))) int int4v;
typedef __attribute__((ext_vector_type(4))) unsigned int uint4v;

#define SCALE_L2E 0.180336880073616f   // 0.125 * log2(e)
#define L2E 1.44269504088896f
#define EBIAS 4.0f                     // E = exp2(s*log2e - EBIAS); scale-invariant

__device__ __forceinline__ float4v mfma16(half8 a, half8 b, float4v c) {
  return __builtin_amdgcn_mfma_f32_16x16x32_f16(a, b, c, 0, 0, 0);
}

__device__ __forceinline__ half8 cvt8(float4v a, float4v b) {
  half8 r;
  r[0] = (f16)a[0]; r[1] = (f16)a[1]; r[2] = (f16)a[2]; r[3] = (f16)a[3];
  r[4] = (f16)b[0]; r[5] = (f16)b[1]; r[6] = (f16)b[2]; r[7] = (f16)b[3];
  return r;
}

// ---------------- mask dtype detection ----------------
__global__ __launch_bounds__(256) void detect_mask_kernel(
    const unsigned int* __restrict__ m, unsigned int* __restrict__ flag) {
  unsigned int v = 0;
  for (int j = threadIdx.x; j < 65536; j += 256)
    if (m[j] > 1u) v = 1u;
  if (v) atomicOr(flag, 1u);
}

// ---------------- batched QKV projection ----------------
// z=0: Qp [tok][512] f16; z=1: Kpk [bh][tok][64]; z=2: Vtt [bh][dv][tok].
__global__ __launch_bounds__(256) void gemm_qkv(
    const float* __restrict__ inQ, const float* __restrict__ inK,
    const float* __restrict__ inV, const float* __restrict__ WQ,
    const float* __restrict__ WK, const float* __restrict__ WV,
    f16* __restrict__ Qp, f16* __restrict__ Kpk, f16* __restrict__ Vtt) {
  __shared__ f16 As[128][40];
  __shared__ f16 Bs[128][40];
  const int z = blockIdx.z;
  const float* A = (z == 0) ? inQ : (z == 1) ? inK : inV;
  const float* W = (z == 0) ? WQ : (z == 1) ? WK : WV;
  const int t = threadIdx.x;
  const int bm = blockIdx.x * 128;
  const int bn = blockIdx.y * 128;
  const int w = t >> 6, ln = t & 63;
  const int wr = w >> 1, wc = w & 1;
  const int lr = ln & 15, lg = ln >> 4;
  const int srow = t >> 1, scol = (t & 1) * 16;

  float4v acc[4][4] = {};

  for (int k0 = 0; k0 < 512; k0 += 32) {
    {
      const float* ap = A + (size_t)(bm + srow) * 512 + k0 + scol;
      float4v x0 = *(const float4v*)ap,       x1 = *(const float4v*)(ap + 4);
      float4v x2 = *(const float4v*)(ap + 8), x3 = *(const float4v*)(ap + 12);
      *(half8*)&As[srow][scol]     = cvt8(x0, x1);
      *(half8*)&As[srow][scol + 8] = cvt8(x2, x3);
    }
    {
      const float* wp = W + (size_t)(bn + srow) * 512 + k0 + scol;
      float4v x0 = *(const float4v*)wp,       x1 = *(const float4v*)(wp + 4);
      float4v x2 = *(const float4v*)(wp + 8), x3 = *(const float4v*)(wp + 12);
      *(half8*)&Bs[srow][scol]     = cvt8(x0, x1);
      *(half8*)&Bs[srow][scol + 8] = cvt8(x2, x3);
    }
    __syncthreads();
    half8 af[4], bf[4];
    #pragma unroll
    for (int m = 0; m < 4; m++) af[m] = *(const half8*)&As[wr * 64 + m * 16 + lr][lg * 8];
    #pragma unroll
    for (int n = 0; n < 4; n++) bf[n] = *(const half8*)&Bs[wc * 64 + n * 16 + lr][lg * 8];
    #pragma unroll
    for (int m = 0; m < 4; m++)
      #pragma unroll
      for (int n = 0; n < 4; n++) acc[m][n] = mfma16(af[m], bf[n], acc[m][n]);
    __syncthreads();
  }

  #pragma unroll
  for (int m = 0; m < 4; m++) {
    int row = bm + wr * 64 + m * 16 + lg * 4;
    #pragma unroll
    for (int n = 0; n < 4; n++) {
      int col = bn + wc * 64 + n * 16 + lr;
      int b_ = row >> 11, s_ = row & 2047, h_ = col >> 6, d_ = col & 63;
      if (z == 0) {
        #pragma unroll
        for (int r = 0; r < 4; r++)
          Qp[(size_t)(row + r) * 512 + col] = (f16)acc[m][n][r];
      } else if (z == 1) {
        #pragma unroll
        for (int r = 0; r < 4; r++)
          Kpk[(((size_t)(b_ * 8 + h_)) * SS + s_ + r) * 64 + d_] = (f16)acc[m][n][r];
      } else {
        half4 ph;
        ph[0] = (f16)acc[m][n][0]; ph[1] = (f16)acc[m][n][1];
        ph[2] = (f16)acc[m][n][2]; ph[3] = (f16)acc[m][n][3];
        *(half4*)&Vtt[(((size_t)(b_ * 8 + h_)) * 64 + d_) * SS + s_] = ph;
      }
    }
  }
}

// ---------------- output GEMM: ctx (f16) x W_fc^T -> fp32 ----------------
__global__ __launch_bounds__(256) void gemm_out(const f16* __restrict__ ctx,
                                                const float* __restrict__ W,
                                                float* __restrict__ Out) {
  __shared__ f16 As[128][40];
  __shared__ f16 Bs[128][40];
  const int t = threadIdx.x;
  const int bm = blockIdx.x * 128;
  const int bn = blockIdx.y * 128;
  const int w = t >> 6, ln = t & 63;
  const int wr = w >> 1, wc = w & 1;
  const int lr = ln & 15, lg = ln >> 4;
  const int srow = t >> 1, scol = (t & 1) * 16;

  float4v acc[4][4] = {};

  for (int k0 = 0; k0 < 512; k0 += 32) {
    {
      const f16* ap = ctx + (size_t)(bm + srow) * 512 + k0 + scol;
      *(half8*)&As[srow][scol]     = *(const half8*)(ap);
      *(half8*)&As[srow][scol + 8] = *(const half8*)(ap + 8);
    }
    {
      const float* wp = W + (size_t)(bn + srow) * 512 + k0 + scol;
      float4v x0 = *(const float4v*)wp,       x1 = *(const float4v*)(wp + 4);
      float4v x2 = *(const float4v*)(wp + 8), x3 = *(const float4v*)(wp + 12);
      *(half8*)&Bs[srow][scol]     = cvt8(x0, x1);
      *(half8*)&Bs[srow][scol + 8] = cvt8(x2, x3);
    }
    __syncthreads();
    half8 af[4], bf[4];
    #pragma unroll
    for (int m = 0; m < 4; m++) af[m] = *(const half8*)&As[wr * 64 + m * 16 + lr][lg * 8];
    #pragma unroll
    for (int n = 0; n < 4; n++) bf[n] = *(const half8*)&Bs[wc * 64 + n * 16 + lr][lg * 8];
    #pragma unroll
    for (int m = 0; m < 4; m++)
      #pragma unroll
      for (int n = 0; n < 4; n++) acc[m][n] = mfma16(af[m], bf[n], acc[m][n]);
    __syncthreads();
  }

  #pragma unroll
  for (int m = 0; m < 4; m++) {
    int row = bm + wr * 64 + m * 16 + lg * 4;
    #pragma unroll
    for (int n = 0; n < 4; n++) {
      int col = bn + wc * 64 + n * 16 + lr;
      #pragma unroll
      for (int r = 0; r < 4; r++)
        Out[(size_t)(row + r) * 512 + col] = acc[m][n][r];
    }
  }
}

// ---------------- phase 1: scores -> E (unnormalized exp, f16) + row sums ----------------
// Block = (b, kh, qblk 32 rows).  bid&7 = (b,kh) -> XCD L2 locality for K.
// other+mask staged once per kt (double-buffered, 1 barrier/kt), reused by
// all 8 heads.  K/Q direct from L2.  E written [bh][q][k] f16.
__global__ __launch_bounds__(256, 4) void attn_scores(
    const f16* __restrict__ Qp, const f16* __restrict__ Kpk,
    const float* __restrict__ other, const unsigned char* __restrict__ mask8,
    const int* __restrict__ mask32, const unsigned int* __restrict__ flag,
    float* __restrict__ lsum2, f16* __restrict__ Epk) {
  __shared__ char smem_raw[2 * 16896 + 4096];
  float* othm0 = (float*)smem_raw;              // [32][132]
  float* othm1 = (float*)(smem_raw + 16896);
  float* red   = (float*)(smem_raw + 2 * 16896);  // [4][8][32]

  const int t = threadIdx.x;
  const int bid = blockIdx.x;
  const int b  = (bid & 7) >> 1;
  const int kh = bid & 1;
  const int qblk = (bid >> 3) * 32;
  const int w = t >> 6, ln = t & 63;
  const int lr = ln & 15, lg = ln >> 4;
  const bool use8 = (*flag) != 0;

  float rs[8][2];
  #pragma unroll
  for (int hh = 0; hh < 8; hh++) { rs[hh][0] = 0.f; rs[hh][1] = 0.f; }

  for (int kt = 0; kt < 8; kt++) {
    const int kb = kh * 1024 + kt * 128;
    float* othm = (kt & 1) ? othm1 : othm0;
    // ---- stage other+mask tile once per kt (scaled by log2e, -EBIAS) ----
    {
      const int q = t >> 3, k0 = (t & 7) * 16;
      const size_t base = ((size_t)b * SS + qblk + q) * SS + kb + k0;
      const float* op = other + base;
      float4v o[4];
      #pragma unroll
      for (int j = 0; j < 4; j++) o[j] = *(const float4v*)(op + j * 4);
      float* od = othm + q * 132 + k0;
      if (use8) {
        uint4v mv = *(const uint4v*)(mask8 + base);
        #pragma unroll
        for (int j = 0; j < 4; j++) {
          unsigned int mm = mv[j];
          float4v r;
          #pragma unroll
          for (int rr = 0; rr < 4; rr++)
            r[rr] = ((mm >> (8 * rr)) & 0xffu) ? -1e9f : fmaf(o[j][rr], L2E, -EBIAS);
          *(float4v*)(od + j * 4) = r;
        }
      } else {
        #pragma unroll
        for (int j = 0; j < 4; j++) {
          int4v m4 = *(const int4v*)(mask32 + base + j * 4);
          float4v r;
          #pragma unroll
          for (int rr = 0; rr < 4; rr++)
            r[rr] = m4[rr] ? -1e9f : fmaf(o[j][rr], L2E, -EBIAS);
          *(float4v*)(od + j * 4) = r;
        }
      }
    }
    __syncthreads();  // othm[kt&1] ready; prev-kt consumers already past
    #pragma unroll
    for (int h = 0; h < 8; h++) {
      const int bh2 = b * 8 + h;
      // Q fragments (L2-hot)
      half8 qf[2][2];
      #pragma unroll
      for (int m = 0; m < 2; m++) {
        const f16* qp = Qp + ((size_t)b * SS + qblk + m * 16 + lr) * 512 + h * 64 + lg * 8;
        qf[m][0] = *(const half8*)qp;
        qf[m][1] = *(const half8*)(qp + 32);
      }
      // K fragments direct (wave-disjoint rows)
      const f16* kbase = Kpk + ((size_t)bh2 * SS + kb + w * 32 + lr) * 64 + lg * 8;
      half8 kf[2][2];
      #pragma unroll
      for (int n = 0; n < 2; n++)
        #pragma unroll
        for (int ks = 0; ks < 2; ks++)
          kf[n][ks] = *(const half8*)(kbase + n * 1024 + ks * 32);
      // QK^T transposed: A = K (rows = k token), B = Q (cols = q)
      float4v sacc[2][2] = {};  // [n (k)][m (q)]
      #pragma unroll
      for (int ks = 0; ks < 2; ks++)
        #pragma unroll
        for (int n = 0; n < 2; n++)
          #pragma unroll
          for (int m = 0; m < 2; m++)
            sacc[n][m] = mfma16(kf[n][ks], qf[m][ks], sacc[n][m]);
      // ---- epilogue: exp2(s*scale + oth) -> E f16 + row-sum accumulate ----
      #pragma unroll
      for (int n = 0; n < 2; n++) {
        #pragma unroll
        for (int m = 0; m < 2; m++) {
          const int q_l = m * 16 + lr;
          const int kc = w * 32 + n * 16 + lg * 4;
          float4v oth = *(const float4v*)(othm + q_l * 132 + kc);
          float4v ev;
          #pragma unroll
          for (int r = 0; r < 4; r++)
            ev[r] = exp2f(fmaf(sacc[n][m][r], SCALE_L2E, oth[r]));
          rs[h][m] += (ev[0] + ev[1]) + (ev[2] + ev[3]);
          half4 eh;
          eh[0] = (f16)ev[0]; eh[1] = (f16)ev[1];
          eh[2] = (f16)ev[2]; eh[3] = (f16)ev[3];
          *(half4*)&Epk[((size_t)bh2 * SS + qblk + q_l) * SS + kb + kc] = eh;
        }
      }
    }
  }

  #pragma unroll
  for (int hh = 0; hh < 8; hh++) {
    #pragma unroll
    for (int m = 0; m < 2; m++) {
      float v = rs[hh][m];
      v += __shfl_xor(v, 16);
      v += __shfl_xor(v, 32);
      if (ln < 16) red[(w * 8 + hh) * 32 + m * 16 + lr] = v;
    }
  }
  __syncthreads();
  {
    const int h = t >> 5, q = t & 31;
    float tot = red[(0 + h) * 32 + q] + red[(8 + h) * 32 + q] +
                (red[(16 + h) * 32 + q] + red[(24 + h) * 32 + q]);
    lsum2[(size_t)kh * BHN * SS + (size_t)(b * 8 + h) * SS + qblk + q] = tot;
  }
}

// ---------------- phase 2: normalize E -> attn (fp32) + PV -> ctx ----------------
// Pure streaming: no LDS, no barriers.  Block = (bh, 64 q rows); wave w owns
// 16 q rows.  E half8 load IS the PV A-fragment (lane&15 = q row).  Full-line
// nontemporal attn stores (128 B per 16-row quad).
__global__ __launch_bounds__(256, 4) void attn_norm_pv(
    const f16* __restrict__ Epk, const f16* __restrict__ Vtt,
    const float* __restrict__ lsum2, float* __restrict__ attn_out,
    f16* __restrict__ ctx) {
  const int t = threadIdx.x;
  const int bid = blockIdx.x;
  const int bh = (bid & 7) * 4 + ((bid >> 3) & 3);  // 4 heads per XCD
  const int qt = bid >> 5;                          // 0..31
  const int b = bh >> 3, h = bh & 7;
  const int w = t >> 6, ln = t & 63;
  const int lr = ln & 15, lg = ln >> 4;
  const int qrow = qt * 64 + w * 16 + lr;           // A-operand row

  const size_t qi = (size_t)bh * SS + qrow;
  const float invl = 1.0f / (lsum2[qi] + lsum2[(size_t)BHN * SS + qi]);

  const f16* Eb = Epk + ((size_t)bh * SS + qrow) * SS;
  float* Ab = attn_out + ((size_t)bh * SS + qrow) * SS;
  const f16* Vb = Vtt + (size_t)bh * 64 * SS;

  float4v cacc[4] = {};

  #pragma unroll 2
  for (int kb = 0; kb < SS; kb += 32) {
    half8 eh = *(const half8*)(Eb + kb + lg * 8);
    float4v a0, a1;
    #pragma unroll
    for (int r = 0; r < 4; r++) {
      a0[r] = (float)eh[r] * invl;
      a1[r] = (float)eh[4 + r] * invl;
    }
    __builtin_nontemporal_store(a0, (float4v*)(Ab + kb + lg * 8));
    __builtin_nontemporal_store(a1, (float4v*)(Ab + kb + lg * 8 + 4));
    half8 pf = cvt8(a0, a1);
    #pragma unroll
    for (int n = 0; n < 4; n++) {
      half8 vf = *(const half8*)(Vb + (size_t)(n * 16 + lr) * SS + kb + lg * 8);
      cacc[n] = mfma16(pf, vf, cacc[n]);
    }
  }

  // ctx[b*S + qt*64 + w*16 + lg*4 + r][h*64 + n*16 + lr]
  #pragma unroll
  for (int n = 0; n < 4; n++) {
    #pragma unroll
    for (int r = 0; r < 4; r++) {
      ctx[((size_t)b * SS + qt * 64 + w * 16 + lg * 4 + r) * 512 +
          h * 64 + n * 16 + lr] = (f16)cacc[n][r];
    }
  }
}

extern "C" void kernel_launch(void* const* d_in, const int* in_sizes, int n_in,
                              void* d_out, int out_size, void* d_ws, size_t ws_size,
                              hipStream_t stream) {
  const float* inQ   = (const float*)d_in[0];
  const float* inK   = (const float*)d_in[1];
  const float* inV   = (const float*)d_in[2];
  const void*  mask  = d_in[3];
  const float* other = (const float*)d_in[4];
  const float* WQ    = (const float*)d_in[5];
  const float* WK    = (const float*)d_in[6];
  const float* WV    = (const float*)d_in[7];
  const float* WF    = (const float*)d_in[8];

  char* ws = (char*)d_ws;
  size_t off = 0;
  unsigned int* flag = (unsigned int*)(ws + off); off += 256;
  f16* Qp    = (f16*)(ws + off); off += (size_t)MTOK * 512 * 2;
  f16* Kpk   = (f16*)(ws + off); off += (size_t)MTOK * 512 * 2;
  f16* Vtt   = (f16*)(ws + off); off += (size_t)MTOK * 512 * 2;
  float* lsum2 = (float*)(ws + off); off += (size_t)2 * BHN * SS * 4;
  f16* ctx   = (f16*)(ws + off); off += (size_t)MTOK * 512 * 2;
  f16* Epk   = (f16*)(ws + off); off += (size_t)BHN * SS * SS * 2;  // 268 MB
  if (ws_size < off) return;  // ws too small -> clean failure, revert next round

  float* outp  = (float*)d_out;
  float* attnp = outp + (size_t)MTOK * DDIM;

  hipMemsetAsync(flag, 0, 256, stream);
  detect_mask_kernel<<<1, 256, 0, stream>>>((const unsigned int*)mask, flag);

  gemm_qkv<<<dim3(64, 4, 3), 256, 0, stream>>>(inQ, inK, inV, WQ, WK, WV,
                                               Qp, Kpk, Vtt);

  attn_scores<<<512, 256, 0, stream>>>(
      Qp, Kpk, other, (const unsigned char*)mask, (const int*)mask, flag,
      lsum2, Epk);

  attn_norm_pv<<<1024, 256, 0, stream>>>(Epk, Vtt, lsum2, attnp, ctx);

  gemm_out<<<dim3(64, 4), 256, 0, stream>>>(ctx, WF, outp);
}